// Round 1
// baseline (911.065 us; speedup 1.0000x reference)
//
#include <hip/hip_runtime.h>
#include <hip/hip_bf16.h>
#include <cstdint>
#include <cstddef>

typedef __bf16 bf16;
typedef __bf16 bf16x4 __attribute__((ext_vector_type(4)));
typedef __bf16 bf16x8 __attribute__((ext_vector_type(8)));
typedef float  f32x4  __attribute__((ext_vector_type(4)));

#define S_LEN 2048
#define HID   4096
#define NH    32
#define NKV   8
#define HD    128

// ---------------------------------------------------------------------------
// async global->LDS, 16B per lane. LDS dest is wave-uniform base + lane*16.
__device__ __forceinline__ void gload_lds16(const bf16* g, bf16* l) {
    __builtin_amdgcn_global_load_lds(
        (const __attribute__((address_space(1))) void*)g,
        (__attribute__((address_space(3))) void*)l,
        16, 0, 0);
}

// ---------------------------------------------------------------------------
// fp32 -> bf16 cast (vectorized float4 -> bf16x4)
__global__ void cast_f32_bf16(const float* __restrict__ in, bf16* __restrict__ out, int n4) {
    int idx    = blockIdx.x * blockDim.x + threadIdx.x;
    int stride = gridDim.x * blockDim.x;
    for (int i = idx; i < n4; i += stride) {
        float4 v = ((const float4*)in)[i];
        bf16x4 o = { (bf16)v.x, (bf16)v.y, (bf16)v.z, (bf16)v.w };
        ((bf16x4*)out)[i] = o;
    }
}

// ---------------------------------------------------------------------------
// GEMM: C[m][n] = sum_k A[m][k] * B[n][k]   (both K-major; B is a weight [N][K])
// 128x128 tile, BK=32, 256 threads = 4 waves (2x2), each wave 64x64 (4x4 frags),
// 16x16x32 bf16 MFMA, global_load_lds width-16 staging (m97 structure).
template <typename OUT_T>
__global__ __launch_bounds__(256) void gemm_bt(const bf16* __restrict__ A,
                                               const bf16* __restrict__ B,
                                               OUT_T* __restrict__ C,
                                               int M, int N, int K) {
    __shared__ alignas(16) bf16 sA[128 * 32];
    __shared__ alignas(16) bf16 sB[128 * 32];

    const int tid  = threadIdx.x;
    const int lane = tid & 63;
    const int w    = tid >> 6;      // 0..3
    const int wr   = w >> 1;        // wave row (0..1)
    const int wc   = w & 1;         // wave col (0..1)
    const int l15  = lane & 15;
    const int l4   = lane >> 4;
    const int m0   = blockIdx.y * 128;
    const int n0   = blockIdx.x * 128;

    f32x4 acc[4][4] = {};

    // staging: 8 chunks of 1KB per tile; wave w stages chunks w*2, w*2+1
    const int c0 = w * 2;
    const int c1 = w * 2 + 1;
    const int srow0 = c0 * 16 + (lane >> 2);
    const int srow1 = c1 * 16 + (lane >> 2);
    const int scol  = (lane & 3) * 8;
    const bf16* aS0 = A + (size_t)(m0 + srow0) * K + scol;
    const bf16* aS1 = A + (size_t)(m0 + srow1) * K + scol;
    const bf16* bS0 = B + (size_t)(n0 + srow0) * K + scol;
    const bf16* bS1 = B + (size_t)(n0 + srow1) * K + scol;
    bf16* aD0 = &sA[c0 * 512];
    bf16* aD1 = &sA[c1 * 512];
    bf16* bD0 = &sB[c0 * 512];
    bf16* bD1 = &sB[c1 * 512];

    for (int k0 = 0; k0 < K; k0 += 32) {
        gload_lds16(aS0 + k0, aD0);
        gload_lds16(aS1 + k0, aD1);
        gload_lds16(bS0 + k0, bD0);
        gload_lds16(bS1 + k0, bD1);
        __syncthreads();

        bf16x8 af[4], bfr[4];
#pragma unroll
        for (int i = 0; i < 4; ++i)
            af[i] = *(const bf16x8*)&sA[(wr * 64 + i * 16 + l15) * 32 + l4 * 8];
#pragma unroll
        for (int j = 0; j < 4; ++j)
            bfr[j] = *(const bf16x8*)&sB[(wc * 64 + j * 16 + l15) * 32 + l4 * 8];
#pragma unroll
        for (int i = 0; i < 4; ++i)
#pragma unroll
            for (int j = 0; j < 4; ++j)
                acc[i][j] = __builtin_amdgcn_mfma_f32_16x16x32_bf16(af[i], bfr[j], acc[i][j], 0, 0, 0);
        __syncthreads();
    }

    // epilogue: C/D layout col = lane&15, row = (lane>>4)*4 + reg
#pragma unroll
    for (int i = 0; i < 4; ++i) {
        const int row = m0 + wr * 64 + i * 16 + l4 * 4;
#pragma unroll
        for (int j = 0; j < 4; ++j) {
            const int col = n0 + wc * 64 + j * 16 + l15;
#pragma unroll
            for (int r = 0; r < 4; ++r)
                C[(size_t)(row + r) * N + col] = (OUT_T)acc[i][j][r];
        }
    }
}

// ---------------------------------------------------------------------------
// Flash attention, causal, GQA 4:1. Block = 4 waves, 64 q-rows (16/wave).
// Q: [S][NH*HD] bf16 (head h cols h*128..), K/V: [S][NKV*HD] bf16.
__global__ __launch_bounds__(256) void attn_kernel(const bf16* __restrict__ Q,
                                                   const bf16* __restrict__ Kp,
                                                   const bf16* __restrict__ Vp,
                                                   bf16* __restrict__ O) {
    __shared__ alignas(16) bf16 sK[64 * 128];   // [s][d]
    __shared__ alignas(16) bf16 sVt[128 * 64];  // [d][s]
    __shared__ alignas(16) bf16 sP[4][16 * 64]; // per-wave P

    const int tid  = threadIdx.x;
    const int lane = tid & 63;
    const int w    = tid >> 6;
    const int l15  = lane & 15;
    const int l4   = lane >> 4;
    const int h    = blockIdx.y;
    const int hk   = h >> 2;
    const int q0   = blockIdx.x * 64;
    const float scale = 0.08838834764831845f; // 1/sqrt(128)

    // Q fragments (held in registers for whole kernel)
    bf16x8 qf[4];
    const int qrow = q0 + w * 16 + l15;
#pragma unroll
    for (int ks = 0; ks < 4; ++ks)
        qf[ks] = *(const bf16x8*)(Q + (size_t)qrow * HID + h * HD + ks * 32 + l4 * 8);

    f32x4 acc_o[8] = {};
    float mrow[4], lrow[4];
#pragma unroll
    for (int i = 0; i < 4; ++i) { mrow[i] = -1e30f; lrow[i] = 0.f; }

    const int nt = blockIdx.x + 1;  // causal: tiles 0..q-tile
    for (int t = 0; t < nt; ++t) {
        const int s0 = t * 64;
        // stage K tile [64][128] via global_load_lds: 16 chunks, 4/wave
#pragma unroll
        for (int j = 0; j < 4; ++j) {
            const int c   = w * 4 + j;
            const int row = c * 4 + (lane >> 4);
            const int col = (lane & 15) * 8;
            gload_lds16(Kp + (size_t)(s0 + row) * (NKV * HD) + hk * HD + col, &sK[c * 512]);
        }
        // stage V transposed (reg-staged scalar writes)
#pragma unroll
        for (int r2 = 0; r2 < 4; ++r2) {
            const int srow = r2 * 16 + (tid >> 4);
            const int d0   = (tid & 15) * 8;
            bf16x8 v = *(const bf16x8*)(Vp + (size_t)(s0 + srow) * (NKV * HD) + hk * HD + d0);
#pragma unroll
            for (int e = 0; e < 8; ++e) sVt[(d0 + e) * 64 + srow] = v[e];
        }
        __syncthreads();

        // QK^T: each wave: its 16 q-rows x all 64 s-cols
        f32x4 accs[4] = {};
#pragma unroll
        for (int ks = 0; ks < 4; ++ks) {
#pragma unroll
            for (int j = 0; j < 4; ++j) {
                bf16x8 kb = *(const bf16x8*)&sK[(j * 16 + l15) * 128 + ks * 32 + l4 * 8];
                accs[j] = __builtin_amdgcn_mfma_f32_16x16x32_bf16(qf[ks], kb, accs[j], 0, 0, 0);
            }
        }

        // mask + scale
        float sc[4][4];
        float tmax[4] = {-1e30f, -1e30f, -1e30f, -1e30f};
#pragma unroll
        for (int j = 0; j < 4; ++j) {
            const int scol = s0 + j * 16 + l15;
#pragma unroll
            for (int i = 0; i < 4; ++i) {
                const int r = q0 + w * 16 + l4 * 4 + i;
                float v = accs[j][i] * scale;
                if (scol > r) v = -1e30f;
                sc[j][i] = v;
                tmax[i] = fmaxf(tmax[i], v);
            }
        }
        // row-max reduce across the 16 lanes holding this row group
#pragma unroll
        for (int i = 0; i < 4; ++i) {
#pragma unroll
            for (int msk = 1; msk < 16; msk <<= 1)
                tmax[i] = fmaxf(tmax[i], __shfl_xor(tmax[i], msk));
        }
        float alpha[4];
#pragma unroll
        for (int i = 0; i < 4; ++i) {
            const float nm = fmaxf(mrow[i], tmax[i]);
            alpha[i] = __expf(mrow[i] - nm);
            mrow[i]  = nm;
        }
        float rsum[4] = {0.f, 0.f, 0.f, 0.f};
#pragma unroll
        for (int j = 0; j < 4; ++j)
#pragma unroll
            for (int i = 0; i < 4; ++i) {
                const float p = __expf(sc[j][i] - mrow[i]);
                sc[j][i] = p;
                rsum[i] += p;
            }
#pragma unroll
        for (int i = 0; i < 4; ++i) {
#pragma unroll
            for (int msk = 1; msk < 16; msk <<= 1)
                rsum[i] += __shfl_xor(rsum[i], msk);
            lrow[i] = lrow[i] * alpha[i] + rsum[i];
        }
#pragma unroll
        for (int d = 0; d < 8; ++d)
#pragma unroll
            for (int i = 0; i < 4; ++i) acc_o[d][i] *= alpha[i];

        // P -> LDS (bf16), per-wave buffer
#pragma unroll
        for (int j = 0; j < 4; ++j)
#pragma unroll
            for (int i = 0; i < 4; ++i)
                sP[w][(l4 * 4 + i) * 64 + j * 16 + l15] = (bf16)sc[j][i];
        __syncthreads();

        // PV: out[16][128] += P[16][64] * V[64][128]
#pragma unroll
        for (int kk = 0; kk < 2; ++kk) {
            bf16x8 pa = *(const bf16x8*)&sP[w][l15 * 64 + kk * 32 + l4 * 8];
#pragma unroll
            for (int d = 0; d < 8; ++d) {
                bf16x8 vb = *(const bf16x8*)&sVt[(d * 16 + l15) * 64 + kk * 32 + l4 * 8];
                acc_o[d] = __builtin_amdgcn_mfma_f32_16x16x32_bf16(pa, vb, acc_o[d], 0, 0, 0);
            }
        }
        __syncthreads();
    }

    // epilogue: normalize and store
#pragma unroll
    for (int d = 0; d < 8; ++d)
#pragma unroll
        for (int i = 0; i < 4; ++i) {
            const float v = acc_o[d][i] / lrow[i];
            O[(size_t)(q0 + w * 16 + l4 * 4 + i) * HID + h * HD + d * 16 + l15] = (bf16)v;
        }
}

// ---------------------------------------------------------------------------
extern "C" void kernel_launch(void* const* d_in, const int* in_sizes, int n_in,
                              void* d_out, int out_size, void* d_ws, size_t ws_size,
                              hipStream_t stream) {
    const float* hx = (const float*)d_in[0];
    // d_in[1] = attention_mask (exact causal) -- applied analytically
    const float* wq = (const float*)d_in[2];
    const float* wk = (const float*)d_in[3];
    const float* wv = (const float*)d_in[4];
    const float* wo = (const float*)d_in[5];
    float* out = (float*)d_out;

    // workspace layout (bf16), weight buffer reused serially: ~92 MB total
    bf16* Xb   = (bf16*)d_ws;            // 2048*4096
    bf16* Wbuf = Xb + 8388608;           // 4096*4096 (wq / wk / wv / wo reuse)
    bf16* Qb   = Wbuf + 16777216;        // 2048*4096
    bf16* Kb   = Qb + 8388608;           // 2048*1024
    bf16* Vb   = Kb + 2097152;           // 2048*1024
    bf16* Ob   = Vb + 2097152;           // 2048*4096

    auto cast = [&](const float* src, bf16* dst, int n) {
        int n4 = n / 4;
        int blocks = (n4 + 255) / 256;
        if (blocks > 2048) blocks = 2048;
        cast_f32_bf16<<<blocks, 256, 0, stream>>>(src, dst, n4);
    };

    cast(hx, Xb, 2048 * 4096);

    cast(wq, Wbuf, 4096 * 4096);
    gemm_bt<bf16><<<dim3(32, 16), 256, 0, stream>>>(Xb, Wbuf, Qb, 2048, 4096, 4096);

    cast(wk, Wbuf, 1024 * 4096);
    gemm_bt<bf16><<<dim3(8, 16), 256, 0, stream>>>(Xb, Wbuf, Kb, 2048, 1024, 4096);

    cast(wv, Wbuf, 1024 * 4096);
    gemm_bt<bf16><<<dim3(8, 16), 256, 0, stream>>>(Xb, Wbuf, Vb, 2048, 1024, 4096);

    attn_kernel<<<dim3(32, 32), 256, 0, stream>>>(Qb, Kb, Vb, Ob);

    cast(wo, Wbuf, 4096 * 4096);
    gemm_bt<float><<<dim3(32, 16), 256, 0, stream>>>(Ob, Wbuf, out, 2048, 4096, 4096);
}

// Round 2
// 643.280 us; speedup vs baseline: 1.4163x; 1.4163x over previous
//
#include <hip/hip_runtime.h>
#include <hip/hip_bf16.h>
#include <cstdint>
#include <cstddef>

typedef __bf16 bf16;
typedef __bf16 bf16x4 __attribute__((ext_vector_type(4)));
typedef __bf16 bf16x8 __attribute__((ext_vector_type(8)));
typedef float  f32x4  __attribute__((ext_vector_type(4)));

#define S_LEN 2048
#define HID   4096
#define NH    32
#define NKV   8
#define HD    128

// ---------------------------------------------------------------------------
// async global->LDS, 16B per lane. LDS dest is wave-uniform base + lane*16.
__device__ __forceinline__ void gload_lds16(const bf16* g, bf16* l) {
    __builtin_amdgcn_global_load_lds(
        (const __attribute__((address_space(1))) void*)g,
        (__attribute__((address_space(3))) void*)l,
        16, 0, 0);
}

// ---------------------------------------------------------------------------
// fp32 -> bf16 cast (vectorized float4 -> bf16x4)
__global__ void cast_f32_bf16(const float* __restrict__ in, bf16* __restrict__ out, int n4) {
    int idx    = blockIdx.x * blockDim.x + threadIdx.x;
    int stride = gridDim.x * blockDim.x;
    for (int i = idx; i < n4; i += stride) {
        float4 v = ((const float4*)in)[i];
        bf16x4 o = { (bf16)v.x, (bf16)v.y, (bf16)v.z, (bf16)v.w };
        ((bf16x4*)out)[i] = o;
    }
}

// ---------------------------------------------------------------------------
// GEMM: C[m][n] = sum_k A[m][k] * B[n][k]   (both K-major; B is a weight [N][K])
// 128x128 tile, BK=32, 256 threads = 4 waves (2x2), each wave 64x64 (4x4 frags),
// 16x16x32 bf16 MFMA, global_load_lds width-16 staging (m97 structure).
template <typename OUT_T>
__global__ __launch_bounds__(256) void gemm_bt(const bf16* __restrict__ A,
                                               const bf16* __restrict__ B,
                                               OUT_T* __restrict__ C,
                                               int M, int N, int K) {
    __shared__ alignas(16) bf16 sA[128 * 32];
    __shared__ alignas(16) bf16 sB[128 * 32];

    const int tid  = threadIdx.x;
    const int lane = tid & 63;
    const int w    = tid >> 6;      // 0..3
    const int wr   = w >> 1;        // wave row (0..1)
    const int wc   = w & 1;         // wave col (0..1)
    const int l15  = lane & 15;
    const int l4   = lane >> 4;
    const int m0   = blockIdx.y * 128;
    const int n0   = blockIdx.x * 128;

    f32x4 acc[4][4] = {};

    // staging: 8 chunks of 1KB per tile; wave w stages chunks w*2, w*2+1
    const int c0 = w * 2;
    const int c1 = w * 2 + 1;
    const int srow0 = c0 * 16 + (lane >> 2);
    const int srow1 = c1 * 16 + (lane >> 2);
    const int scol  = (lane & 3) * 8;
    const bf16* aS0 = A + (size_t)(m0 + srow0) * K + scol;
    const bf16* aS1 = A + (size_t)(m0 + srow1) * K + scol;
    const bf16* bS0 = B + (size_t)(n0 + srow0) * K + scol;
    const bf16* bS1 = B + (size_t)(n0 + srow1) * K + scol;
    bf16* aD0 = &sA[c0 * 512];
    bf16* aD1 = &sA[c1 * 512];
    bf16* bD0 = &sB[c0 * 512];
    bf16* bD1 = &sB[c1 * 512];

    for (int k0 = 0; k0 < K; k0 += 32) {
        gload_lds16(aS0 + k0, aD0);
        gload_lds16(aS1 + k0, aD1);
        gload_lds16(bS0 + k0, bD0);
        gload_lds16(bS1 + k0, bD1);
        __syncthreads();

        bf16x8 af[4], bfr[4];
#pragma unroll
        for (int i = 0; i < 4; ++i)
            af[i] = *(const bf16x8*)&sA[(wr * 64 + i * 16 + l15) * 32 + l4 * 8];
#pragma unroll
        for (int j = 0; j < 4; ++j)
            bfr[j] = *(const bf16x8*)&sB[(wc * 64 + j * 16 + l15) * 32 + l4 * 8];
#pragma unroll
        for (int i = 0; i < 4; ++i)
#pragma unroll
            for (int j = 0; j < 4; ++j)
                acc[i][j] = __builtin_amdgcn_mfma_f32_16x16x32_bf16(af[i], bfr[j], acc[i][j], 0, 0, 0);
        __syncthreads();
    }

    // epilogue: C/D layout col = lane&15, row = (lane>>4)*4 + reg
#pragma unroll
    for (int i = 0; i < 4; ++i) {
        const int row = m0 + wr * 64 + i * 16 + l4 * 4;
#pragma unroll
        for (int j = 0; j < 4; ++j) {
            const int col = n0 + wc * 64 + j * 16 + l15;
#pragma unroll
            for (int r = 0; r < 4; ++r)
                C[(size_t)(row + r) * N + col] = (OUT_T)acc[i][j][r];
        }
    }
}

// ---------------------------------------------------------------------------
// Flash attention, causal, GQA 4:1. Block = 4 waves, 64 q-rows (16/wave).
// Q: [S][NH*HD] bf16 (head h cols h*128..), K/V: [S][NKV*HD] bf16.
// LDS swizzles (T2): all tiles XOR-swizzled at 16B granularity; K staged via
// global_load_lds with pre-swizzled SOURCE (linear dest, rule #21).
__global__ __launch_bounds__(256) void attn_kernel(const bf16* __restrict__ Q,
                                                   const bf16* __restrict__ Kp,
                                                   const bf16* __restrict__ Vp,
                                                   bf16* __restrict__ O) {
    __shared__ alignas(16) bf16 sK[64 * 128];   // [s][d], elem col ^= (row&7)<<3
    __shared__ alignas(16) bf16 sVt[128 * 64];  // [d][s], elem col ^= (row&7)<<3
    __shared__ alignas(16) bf16 sP[4][16 * 64]; // per-wave, col ^= S2(row)<<3

    const int tid  = threadIdx.x;
    const int lane = tid & 63;
    const int w    = tid >> 6;
    const int l15  = lane & 15;
    const int l4   = lane >> 4;
    const int h    = blockIdx.y;
    const int hk   = h >> 2;
    const int qt   = (int)gridDim.x - 1 - (int)blockIdx.x;  // heavy blocks first
    const int q0   = qt * 64;
    const float scale = 0.08838834764831845f; // 1/sqrt(128)

    // Q fragments (held in registers for whole kernel)
    bf16x8 qf[4];
    const int qrow = q0 + w * 16 + l15;
#pragma unroll
    for (int ks = 0; ks < 4; ++ks)
        qf[ks] = *(const bf16x8*)(Q + (size_t)qrow * HID + h * HD + ks * 32 + l4 * 8);

    f32x4 acc_o[8] = {};
    float mrow[4], lrow[4];
#pragma unroll
    for (int i = 0; i < 4; ++i) { mrow[i] = -1e30f; lrow[i] = 0.f; }

    const int nt = qt + 1;  // causal: tiles 0..q-tile
    for (int t = 0; t < nt; ++t) {
        const int s0 = t * 64;
        // stage K tile [64][128] via global_load_lds: 16 chunks, 4/wave.
        // source col pre-swizzled so linear LDS dest == swizzled layout.
#pragma unroll
        for (int j = 0; j < 4; ++j) {
            const int c   = w * 4 + j;
            const int row = c * 4 + (lane >> 4);
            const int col = ((lane & 15) * 8) ^ ((row & 7) << 3);
            gload_lds16(Kp + (size_t)(s0 + row) * (NKV * HD) + hk * HD + col, &sK[c * 512]);
        }
        // stage V transposed: lane reads V[s0+lane][c*8..+7]; writes are
        // per-e constant-row, banks spread by lane -> conflict-free.
#pragma unroll
        for (int r2 = 0; r2 < 4; ++r2) {
            const int c = r2 * 4 + w;
            bf16x8 v = *(const bf16x8*)(Vp + (size_t)(s0 + lane) * (NKV * HD) + hk * HD + c * 8);
#pragma unroll
            for (int e = 0; e < 8; ++e) {
                const int row = c * 8 + e;                 // d-index; row&7 == e
                sVt[row * 64 + (lane ^ (e << 3))] = v[e];
            }
        }
        __syncthreads();

        // QK^T: each wave: its 16 q-rows x all 64 s-cols
        f32x4 accs[4] = {};
#pragma unroll
        for (int ks = 0; ks < 4; ++ks) {
#pragma unroll
            for (int j = 0; j < 4; ++j) {
                const int krow = j * 16 + l15;
                bf16x8 kb = *(const bf16x8*)&sK[krow * 128 + ((ks * 32 + l4 * 8) ^ ((krow & 7) << 3))];
                accs[j] = __builtin_amdgcn_mfma_f32_16x16x32_bf16(qf[ks], kb, accs[j], 0, 0, 0);
            }
        }

        // mask + scale
        float sc[4][4];
        float tmax[4] = {-1e30f, -1e30f, -1e30f, -1e30f};
#pragma unroll
        for (int j = 0; j < 4; ++j) {
            const int scol = s0 + j * 16 + l15;
#pragma unroll
            for (int i = 0; i < 4; ++i) {
                const int r = q0 + w * 16 + l4 * 4 + i;
                float v = accs[j][i] * scale;
                if (scol > r) v = -1e30f;
                sc[j][i] = v;
                tmax[i] = fmaxf(tmax[i], v);
            }
        }
        // row-max reduce across the 16 lanes holding this row group
#pragma unroll
        for (int i = 0; i < 4; ++i) {
#pragma unroll
            for (int msk = 1; msk < 16; msk <<= 1)
                tmax[i] = fmaxf(tmax[i], __shfl_xor(tmax[i], msk));
        }
        float alpha[4];
#pragma unroll
        for (int i = 0; i < 4; ++i) {
            const float nm = fmaxf(mrow[i], tmax[i]);
            alpha[i] = __expf(mrow[i] - nm);
            mrow[i]  = nm;
        }
        float rsum[4] = {0.f, 0.f, 0.f, 0.f};
#pragma unroll
        for (int j = 0; j < 4; ++j)
#pragma unroll
            for (int i = 0; i < 4; ++i) {
                const float p = __expf(sc[j][i] - mrow[i]);
                sc[j][i] = p;
                rsum[i] += p;
            }
#pragma unroll
        for (int i = 0; i < 4; ++i) {
#pragma unroll
            for (int msk = 1; msk < 16; msk <<= 1)
                rsum[i] += __shfl_xor(rsum[i], msk);
            lrow[i] = lrow[i] * alpha[i] + rsum[i];
        }
#pragma unroll
        for (int d = 0; d < 8; ++d)
#pragma unroll
            for (int i = 0; i < 4; ++i) acc_o[d][i] *= alpha[i];

        // P -> LDS (bf16), per-wave buffer (wave-private: no barrier needed)
#pragma unroll
        for (int j = 0; j < 4; ++j)
#pragma unroll
            for (int i = 0; i < 4; ++i) {
                const int prow = l4 * 4 + i;
                const int s2   = (prow & 7) ^ ((prow >> 3) << 1);
                sP[w][prow * 64 + ((j * 16 + l15) ^ (s2 << 3))] = (bf16)sc[j][i];
            }

        // PV: out[16][128] += P[16][64] * V[64][128]
#pragma unroll
        for (int kk = 0; kk < 2; ++kk) {
            const int s2l = (l15 & 7) ^ ((l15 >> 3) << 1);
            bf16x8 pa = *(const bf16x8*)&sP[w][l15 * 64 + ((kk * 32 + l4 * 8) ^ (s2l << 3))];
#pragma unroll
            for (int d = 0; d < 8; ++d) {
                const int vrow = d * 16 + l15;
                bf16x8 vb = *(const bf16x8*)&sVt[vrow * 64 + ((kk * 32 + l4 * 8) ^ ((vrow & 7) << 3))];
                acc_o[d] = __builtin_amdgcn_mfma_f32_16x16x32_bf16(pa, vb, acc_o[d], 0, 0, 0);
            }
        }
        __syncthreads();
    }

    // epilogue: normalize and store
#pragma unroll
    for (int d = 0; d < 8; ++d)
#pragma unroll
        for (int i = 0; i < 4; ++i) {
            const float v = acc_o[d][i] / lrow[i];
            O[(size_t)(q0 + w * 16 + l4 * 4 + i) * HID + h * HD + d * 16 + l15] = (bf16)v;
        }
}

// ---------------------------------------------------------------------------
extern "C" void kernel_launch(void* const* d_in, const int* in_sizes, int n_in,
                              void* d_out, int out_size, void* d_ws, size_t ws_size,
                              hipStream_t stream) {
    const float* hx = (const float*)d_in[0];
    // d_in[1] = attention_mask (exact causal) -- applied analytically
    const float* wq = (const float*)d_in[2];
    const float* wk = (const float*)d_in[3];
    const float* wv = (const float*)d_in[4];
    const float* wo = (const float*)d_in[5];
    float* out = (float*)d_out;

    // workspace layout (bf16), weight buffer reused serially: ~92 MB total
    bf16* Xb   = (bf16*)d_ws;            // 2048*4096
    bf16* Wbuf = Xb + 8388608;           // 4096*4096 (wq / wk / wv / wo reuse)
    bf16* Qb   = Wbuf + 16777216;        // 2048*4096
    bf16* Kb   = Qb + 8388608;           // 2048*1024
    bf16* Vb   = Kb + 2097152;           // 2048*1024
    bf16* Ob   = Vb + 2097152;           // 2048*4096

    auto cast = [&](const float* src, bf16* dst, int n) {
        int n4 = n / 4;
        int blocks = (n4 + 255) / 256;
        if (blocks > 2048) blocks = 2048;
        cast_f32_bf16<<<blocks, 256, 0, stream>>>(src, dst, n4);
    };

    cast(hx, Xb, 2048 * 4096);

    cast(wq, Wbuf, 4096 * 4096);
    gemm_bt<bf16><<<dim3(32, 16), 256, 0, stream>>>(Xb, Wbuf, Qb, 2048, 4096, 4096);

    cast(wk, Wbuf, 1024 * 4096);
    gemm_bt<bf16><<<dim3(8, 16), 256, 0, stream>>>(Xb, Wbuf, Kb, 2048, 1024, 4096);

    cast(wv, Wbuf, 1024 * 4096);
    gemm_bt<bf16><<<dim3(8, 16), 256, 0, stream>>>(Xb, Wbuf, Vb, 2048, 1024, 4096);

    attn_kernel<<<dim3(32, 32), 256, 0, stream>>>(Qb, Kb, Vb, Ob);

    cast(wo, Wbuf, 4096 * 4096);
    gemm_bt<float><<<dim3(32, 16), 256, 0, stream>>>(Ob, Wbuf, out, 2048, 4096, 4096);
}

// Round 3
// 635.698 us; speedup vs baseline: 1.4332x; 1.0119x over previous
//
#include <hip/hip_runtime.h>
#include <hip/hip_bf16.h>
#include <cstdint>
#include <cstddef>

typedef __bf16 bf16;
typedef __bf16 bf16x4 __attribute__((ext_vector_type(4)));
typedef __bf16 bf16x8 __attribute__((ext_vector_type(8)));
typedef float  f32x4  __attribute__((ext_vector_type(4)));

#define S_LEN 2048
#define HID   4096
#define NH    32
#define NKV   8
#define HD    128

// ---------------------------------------------------------------------------
// async global->LDS, 16B per lane. LDS dest is wave-uniform base + lane*16.
__device__ __forceinline__ void gload_lds16(const bf16* g, bf16* l) {
    __builtin_amdgcn_global_load_lds(
        (const __attribute__((address_space(1))) void*)g,
        (__attribute__((address_space(3))) void*)l,
        16, 0, 0);
}

// ---------------------------------------------------------------------------
// fp32 -> bf16 cast (vectorized float4 -> bf16x4)
__global__ void cast_f32_bf16(const float* __restrict__ in, bf16* __restrict__ out, int n4) {
    int idx    = blockIdx.x * blockDim.x + threadIdx.x;
    int stride = gridDim.x * blockDim.x;
    for (int i = idx; i < n4; i += stride) {
        float4 v = ((const float4*)in)[i];
        bf16x4 o = { (bf16)v.x, (bf16)v.y, (bf16)v.z, (bf16)v.w };
        ((bf16x4*)out)[i] = o;
    }
}

// ---------------------------------------------------------------------------
// GEMM: C[m][n] = sum_k A[m][k] * B[n][k]   (both K-major; B is a weight [N][K])
// 128x128 tile, BK=32, 256 threads = 4 waves (2x2), each wave 64x64 (4x4 frags),
// 16x16x32 bf16 MFMA, global_load_lds width-16 staging (m97 structure).
template <typename OUT_T>
__global__ __launch_bounds__(256) void gemm_bt(const bf16* __restrict__ A,
                                               const bf16* __restrict__ B,
                                               OUT_T* __restrict__ C,
                                               int M, int N, int K) {
    __shared__ alignas(16) bf16 sA[128 * 32];
    __shared__ alignas(16) bf16 sB[128 * 32];

    const int tid  = threadIdx.x;
    const int lane = tid & 63;
    const int w    = tid >> 6;      // 0..3
    const int wr   = w >> 1;        // wave row (0..1)
    const int wc   = w & 1;         // wave col (0..1)
    const int l15  = lane & 15;
    const int l4   = lane >> 4;
    const int m0   = blockIdx.y * 128;
    const int n0   = blockIdx.x * 128;

    f32x4 acc[4][4] = {};

    // staging: 8 chunks of 1KB per tile; wave w stages chunks w*2, w*2+1
    const int c0 = w * 2;
    const int c1 = w * 2 + 1;
    const int srow0 = c0 * 16 + (lane >> 2);
    const int srow1 = c1 * 16 + (lane >> 2);
    const int scol  = (lane & 3) * 8;
    const bf16* aS0 = A + (size_t)(m0 + srow0) * K + scol;
    const bf16* aS1 = A + (size_t)(m0 + srow1) * K + scol;
    const bf16* bS0 = B + (size_t)(n0 + srow0) * K + scol;
    const bf16* bS1 = B + (size_t)(n0 + srow1) * K + scol;
    bf16* aD0 = &sA[c0 * 512];
    bf16* aD1 = &sA[c1 * 512];
    bf16* bD0 = &sB[c0 * 512];
    bf16* bD1 = &sB[c1 * 512];

    for (int k0 = 0; k0 < K; k0 += 32) {
        gload_lds16(aS0 + k0, aD0);
        gload_lds16(aS1 + k0, aD1);
        gload_lds16(bS0 + k0, bD0);
        gload_lds16(bS1 + k0, bD1);
        __syncthreads();

        bf16x8 af[4], bfr[4];
#pragma unroll
        for (int i = 0; i < 4; ++i)
            af[i] = *(const bf16x8*)&sA[(wr * 64 + i * 16 + l15) * 32 + l4 * 8];
#pragma unroll
        for (int j = 0; j < 4; ++j)
            bfr[j] = *(const bf16x8*)&sB[(wc * 64 + j * 16 + l15) * 32 + l4 * 8];
#pragma unroll
        for (int i = 0; i < 4; ++i)
#pragma unroll
            for (int j = 0; j < 4; ++j)
                acc[i][j] = __builtin_amdgcn_mfma_f32_16x16x32_bf16(af[i], bfr[j], acc[i][j], 0, 0, 0);
        __syncthreads();
    }

    // epilogue: C/D layout col = lane&15, row = (lane>>4)*4 + reg
#pragma unroll
    for (int i = 0; i < 4; ++i) {
        const int row = m0 + wr * 64 + i * 16 + l4 * 4;
#pragma unroll
        for (int j = 0; j < 4; ++j) {
            const int col = n0 + wc * 64 + j * 16 + l15;
#pragma unroll
            for (int r = 0; r < 4; ++r)
                C[(size_t)(row + r) * N + col] = (OUT_T)acc[i][j][r];
        }
    }
}

// ---------------------------------------------------------------------------
// Flash attention, causal, GQA 4:1. Block = 4 waves, 64 q-rows (16/wave).
// Double-buffered K (gload_lds, pre-swizzled source) and V (reg-staged,
// transposed+swizzled LDS write). One barrier per tile; prefetch of tile t+1
// overlaps compute of tile t (T14).
__global__ __launch_bounds__(256) void attn_kernel(const bf16* __restrict__ Q,
                                                   const bf16* __restrict__ Kp,
                                                   const bf16* __restrict__ Vp,
                                                   bf16* __restrict__ O) {
    __shared__ alignas(16) bf16 sK[2][64 * 128];   // [s][d], elem col ^= (row&7)<<3
    __shared__ alignas(16) bf16 sVt[2][128 * 64];  // [d][s], elem col ^= (row&7)<<3
    __shared__ alignas(16) bf16 sP[4][16 * 64];    // per-wave, col ^= S2(row)<<3

    const int tid  = threadIdx.x;
    const int lane = tid & 63;
    const int w    = tid >> 6;
    const int l15  = lane & 15;
    const int l4   = lane >> 4;
    const int h    = blockIdx.y;
    const int hk   = h >> 2;
    const int qt   = (int)gridDim.x - 1 - (int)blockIdx.x;  // heavy blocks first
    const int q0   = qt * 64;
    const float scale = 0.08838834764831845f; // 1/sqrt(128)

    const bf16* Kbase = Kp + hk * HD;
    const bf16* Vbase = Vp + hk * HD;

    // Q fragments (held in registers for whole kernel)
    bf16x8 qf[4];
    const int qrow = q0 + w * 16 + l15;
#pragma unroll
    for (int ks = 0; ks < 4; ++ks)
        qf[ks] = *(const bf16x8*)(Q + (size_t)qrow * HID + h * HD + ks * 32 + l4 * 8);

    f32x4 acc_o[8] = {};
    float mrow[4], lrow[4];
#pragma unroll
    for (int i = 0; i < 4; ++i) { mrow[i] = -1e30f; lrow[i] = 0.f; }

    // --- staging helpers ---
    auto stageK = [&](int t, int buf) {
#pragma unroll
        for (int j = 0; j < 4; ++j) {
            const int c   = w * 4 + j;
            const int row = c * 4 + l4;
            const int col = (l15 * 8) ^ ((row & 7) << 3);
            gload_lds16(Kbase + (size_t)(t * 64 + row) * (NKV * HD) + col, &sK[buf][c * 512]);
        }
    };
    auto loadV = [&](int t, bf16x8* vr) {
#pragma unroll
        for (int r2 = 0; r2 < 4; ++r2) {
            const int c = r2 * 4 + w;
            vr[r2] = *(const bf16x8*)(Vbase + (size_t)(t * 64 + lane) * (NKV * HD) + c * 8);
        }
    };
    auto writeV = [&](const bf16x8* vr, int buf) {
#pragma unroll
        for (int r2 = 0; r2 < 4; ++r2) {
            const int c = r2 * 4 + w;
#pragma unroll
            for (int e = 0; e < 8; ++e) {
                const int row = c * 8 + e;                 // d-index; row&7 == e
                sVt[buf][row * 64 + (lane ^ (e << 3))] = vr[r2][e];
            }
        }
    };

    const int nt = qt + 1;  // causal: tiles 0..q-tile

    // prologue: stage tile 0 into buf 0
    bf16x8 vreg[4];
    loadV(0, vreg);
    stageK(0, 0);
    writeV(vreg, 0);
    __syncthreads();

    int cur = 0;
    for (int t = 0; t < nt; ++t) {
        const int s0 = t * 64;
        const bool pf = (t + 1 < nt);
        if (pf) {               // issue next-tile loads early (latency hides under compute)
            loadV(t + 1, vreg); // V first: its reg-use wait leaves K gload_lds in flight
            stageK(t + 1, cur ^ 1);
        }

        // QK^T: each wave: its 16 q-rows x all 64 s-cols
        f32x4 accs[4] = {};
#pragma unroll
        for (int ks = 0; ks < 4; ++ks) {
#pragma unroll
            for (int j = 0; j < 4; ++j) {
                const int krow = j * 16 + l15;
                bf16x8 kb = *(const bf16x8*)&sK[cur][krow * 128 + ((ks * 32 + l4 * 8) ^ ((krow & 7) << 3))];
                accs[j] = __builtin_amdgcn_mfma_f32_16x16x32_bf16(qf[ks], kb, accs[j], 0, 0, 0);
            }
        }

        // mask + scale
        float sc[4][4];
        float tmax[4] = {-1e30f, -1e30f, -1e30f, -1e30f};
#pragma unroll
        for (int j = 0; j < 4; ++j) {
            const int scol = s0 + j * 16 + l15;
#pragma unroll
            for (int i = 0; i < 4; ++i) {
                const int r = q0 + w * 16 + l4 * 4 + i;
                float v = accs[j][i] * scale;
                if (scol > r) v = -1e30f;
                sc[j][i] = v;
                tmax[i] = fmaxf(tmax[i], v);
            }
        }
        // row-max reduce across the 16 lanes holding this row group
#pragma unroll
        for (int i = 0; i < 4; ++i) {
#pragma unroll
            for (int msk = 1; msk < 16; msk <<= 1)
                tmax[i] = fmaxf(tmax[i], __shfl_xor(tmax[i], msk));
        }
        float alpha[4];
#pragma unroll
        for (int i = 0; i < 4; ++i) {
            const float nm = fmaxf(mrow[i], tmax[i]);
            alpha[i] = __expf(mrow[i] - nm);
            mrow[i]  = nm;
        }
        float rsum[4] = {0.f, 0.f, 0.f, 0.f};
#pragma unroll
        for (int j = 0; j < 4; ++j)
#pragma unroll
            for (int i = 0; i < 4; ++i) {
                const float p = __expf(sc[j][i] - mrow[i]);
                sc[j][i] = p;
                rsum[i] += p;
            }
#pragma unroll
        for (int i = 0; i < 4; ++i) {
#pragma unroll
            for (int msk = 1; msk < 16; msk <<= 1)
                rsum[i] += __shfl_xor(rsum[i], msk);
            lrow[i] = lrow[i] * alpha[i] + rsum[i];
        }
#pragma unroll
        for (int d = 0; d < 8; ++d)
#pragma unroll
            for (int i = 0; i < 4; ++i) acc_o[d][i] *= alpha[i];

        // P -> LDS (bf16), per-wave buffer (wave-private: no barrier needed)
#pragma unroll
        for (int j = 0; j < 4; ++j)
#pragma unroll
            for (int i = 0; i < 4; ++i) {
                const int prow = l4 * 4 + i;
                const int s2   = (prow & 7) ^ ((prow >> 3) << 1);
                sP[w][prow * 64 + ((j * 16 + l15) ^ (s2 << 3))] = (bf16)sc[j][i];
            }

        // PV: out[16][128] += P[16][64] * V[64][128]
#pragma unroll
        for (int kk = 0; kk < 2; ++kk) {
            const int s2l = (l15 & 7) ^ ((l15 >> 3) << 1);
            bf16x8 pa = *(const bf16x8*)&sP[w][l15 * 64 + ((kk * 32 + l4 * 8) ^ (s2l << 3))];
#pragma unroll
            for (int d = 0; d < 8; ++d) {
                const int vrow = d * 16 + l15;
                bf16x8 vb = *(const bf16x8*)&sVt[cur][vrow * 64 + ((kk * 32 + l4 * 8) ^ ((vrow & 7) << 3))];
                acc_o[d] = __builtin_amdgcn_mfma_f32_16x16x32_bf16(pa, vb, acc_o[d], 0, 0, 0);
            }
        }

        // write prefetched V into the other buffer (nobody reads it yet)
        if (pf) writeV(vreg, cur ^ 1);

        __syncthreads();   // drains vmcnt (K gload_lds) + lgkm; buffers swap
        cur ^= 1;
    }

    // epilogue: normalize (reciprocal, not divide) and store
    float rinv[4];
#pragma unroll
    for (int i = 0; i < 4; ++i) rinv[i] = __frcp_rn(lrow[i]);
#pragma unroll
    for (int d = 0; d < 8; ++d)
#pragma unroll
        for (int i = 0; i < 4; ++i) {
            const float v = acc_o[d][i] * rinv[i];
            O[(size_t)(q0 + w * 16 + l4 * 4 + i) * HID + h * HD + d * 16 + l15] = (bf16)v;
        }
}

// ---------------------------------------------------------------------------
extern "C" void kernel_launch(void* const* d_in, const int* in_sizes, int n_in,
                              void* d_out, int out_size, void* d_ws, size_t ws_size,
                              hipStream_t stream) {
    const float* hx = (const float*)d_in[0];
    // d_in[1] = attention_mask (exact causal) -- applied analytically
    const float* wq = (const float*)d_in[2];
    const float* wk = (const float*)d_in[3];
    const float* wv = (const float*)d_in[4];
    const float* wo = (const float*)d_in[5];
    float* out = (float*)d_out;

    // workspace layout (bf16), weight buffer reused serially: ~92 MB total
    bf16* Xb   = (bf16*)d_ws;            // 2048*4096
    bf16* Wbuf = Xb + 8388608;           // 4096*4096 (wq / wk / wv / wo reuse)
    bf16* Qb   = Wbuf + 16777216;        // 2048*4096
    bf16* Kb   = Qb + 8388608;           // 2048*1024
    bf16* Vb   = Kb + 2097152;           // 2048*1024
    bf16* Ob   = Vb + 2097152;           // 2048*4096

    auto cast = [&](const float* src, bf16* dst, int n) {
        int n4 = n / 4;
        int blocks = (n4 + 255) / 256;
        if (blocks > 2048) blocks = 2048;
        cast_f32_bf16<<<blocks, 256, 0, stream>>>(src, dst, n4);
    };

    cast(hx, Xb, 2048 * 4096);

    cast(wq, Wbuf, 4096 * 4096);
    gemm_bt<bf16><<<dim3(32, 16), 256, 0, stream>>>(Xb, Wbuf, Qb, 2048, 4096, 4096);

    cast(wk, Wbuf, 1024 * 4096);
    gemm_bt<bf16><<<dim3(8, 16), 256, 0, stream>>>(Xb, Wbuf, Kb, 2048, 1024, 4096);

    cast(wv, Wbuf, 1024 * 4096);
    gemm_bt<bf16><<<dim3(8, 16), 256, 0, stream>>>(Xb, Wbuf, Vb, 2048, 1024, 4096);

    attn_kernel<<<dim3(32, 32), 256, 0, stream>>>(Qb, Kb, Vb, Ob);

    cast(wo, Wbuf, 4096 * 4096);
    gemm_bt<float><<<dim3(32, 16), 256, 0, stream>>>(Ob, Wbuf, out, 2048, 4096, 4096);
}

// Round 4
// 524.821 us; speedup vs baseline: 1.7360x; 1.2113x over previous
//
#include <hip/hip_runtime.h>
#include <hip/hip_bf16.h>
#include <cstdint>
#include <cstddef>

typedef __bf16 bf16;
typedef __bf16 bf16x4 __attribute__((ext_vector_type(4)));
typedef __bf16 bf16x8 __attribute__((ext_vector_type(8)));
typedef float  f32x4  __attribute__((ext_vector_type(4)));

#define S_LEN 2048
#define HID   4096
#define NH    32
#define NKV   8
#define HD    128
#define KVLD  2048   // merged K|V buffer row stride

// ---------------------------------------------------------------------------
// async global->LDS, 16B per lane. LDS dest is wave-uniform base + lane*16.
__device__ __forceinline__ void gload_lds16(const bf16* g, bf16* l) {
    __builtin_amdgcn_global_load_lds(
        (const __attribute__((address_space(1))) void*)g,
        (__attribute__((address_space(3))) void*)l,
        16, 0, 0);
}

// ---------------------------------------------------------------------------
// fp32 -> bf16 cast (vectorized float4 -> bf16x4)
__global__ void cast_f32_bf16(const float* __restrict__ in, bf16* __restrict__ out, int n4) {
    int idx    = blockIdx.x * blockDim.x + threadIdx.x;
    int stride = gridDim.x * blockDim.x;
    for (int i = idx; i < n4; i += stride) {
        float4 v = ((const float4*)in)[i];
        bf16x4 o = { (bf16)v.x, (bf16)v.y, (bf16)v.z, (bf16)v.w };
        ((bf16x4*)out)[i] = o;
    }
}

// ---------------------------------------------------------------------------
// GEMM: C[m][n] = sum_k A[m][k] * B[n][k]   (both K-major; B is a weight [N][K])
// 128x128 tile, BK=32, 256 threads = 4 waves (2x2), each wave 64x64 (4x4 frags),
// 16x16x32 bf16 MFMA, global_load_lds width-16 staging (m97 structure).
template <typename OUT_T>
__global__ __launch_bounds__(256) void gemm_bt(const bf16* __restrict__ A,
                                               const bf16* __restrict__ B,
                                               OUT_T* __restrict__ C,
                                               int M, int N, int K) {
    __shared__ alignas(16) bf16 sA[128 * 32];
    __shared__ alignas(16) bf16 sB[128 * 32];

    const int tid  = threadIdx.x;
    const int lane = tid & 63;
    const int w    = tid >> 6;      // 0..3
    const int wr   = w >> 1;        // wave row (0..1)
    const int wc   = w & 1;         // wave col (0..1)
    const int l15  = lane & 15;
    const int l4   = lane >> 4;
    const int m0   = blockIdx.y * 128;
    const int n0   = blockIdx.x * 128;

    f32x4 acc[4][4] = {};

    // staging: 8 chunks of 1KB per tile; wave w stages chunks w*2, w*2+1
    const int c0 = w * 2;
    const int c1 = w * 2 + 1;
    const int srow0 = c0 * 16 + (lane >> 2);
    const int srow1 = c1 * 16 + (lane >> 2);
    const int scol  = (lane & 3) * 8;
    const bf16* aS0 = A + (size_t)(m0 + srow0) * K + scol;
    const bf16* aS1 = A + (size_t)(m0 + srow1) * K + scol;
    const bf16* bS0 = B + (size_t)(n0 + srow0) * K + scol;
    const bf16* bS1 = B + (size_t)(n0 + srow1) * K + scol;
    bf16* aD0 = &sA[c0 * 512];
    bf16* aD1 = &sA[c1 * 512];
    bf16* bD0 = &sB[c0 * 512];
    bf16* bD1 = &sB[c1 * 512];

    for (int k0 = 0; k0 < K; k0 += 32) {
        gload_lds16(aS0 + k0, aD0);
        gload_lds16(aS1 + k0, aD1);
        gload_lds16(bS0 + k0, bD0);
        gload_lds16(bS1 + k0, bD1);
        __syncthreads();

        bf16x8 af[4], bfr[4];
#pragma unroll
        for (int i = 0; i < 4; ++i)
            af[i] = *(const bf16x8*)&sA[(wr * 64 + i * 16 + l15) * 32 + l4 * 8];
#pragma unroll
        for (int j = 0; j < 4; ++j)
            bfr[j] = *(const bf16x8*)&sB[(wc * 64 + j * 16 + l15) * 32 + l4 * 8];
#pragma unroll
        for (int i = 0; i < 4; ++i)
#pragma unroll
            for (int j = 0; j < 4; ++j)
                acc[i][j] = __builtin_amdgcn_mfma_f32_16x16x32_bf16(af[i], bfr[j], acc[i][j], 0, 0, 0);
        __syncthreads();
    }

    // epilogue: C/D layout col = lane&15, row = (lane>>4)*4 + reg
#pragma unroll
    for (int i = 0; i < 4; ++i) {
        const int row = m0 + wr * 64 + i * 16 + l4 * 4;
#pragma unroll
        for (int j = 0; j < 4; ++j) {
            const int col = n0 + wc * 64 + j * 16 + l15;
#pragma unroll
            for (int r = 0; r < 4; ++r)
                C[(size_t)(row + r) * N + col] = (OUT_T)acc[i][j][r];
        }
    }
}

// ---------------------------------------------------------------------------
// Flash attention, causal, GQA 4:1. Block = 8 waves, 128 q-rows (16/wave).
// Double-buffered K (gload_lds, pre-swizzled source) and V (reg-staged,
// transposed+swizzled LDS write). One barrier per tile. K/V from the merged
// [S][KVLD] buffer (K cols 0..1023, V cols 1024..2047).
__global__ __launch_bounds__(512) void attn_kernel(const bf16* __restrict__ Q,
                                                   const bf16* __restrict__ Kp,
                                                   const bf16* __restrict__ Vp,
                                                   bf16* __restrict__ O) {
    __shared__ alignas(16) bf16 sK[2][64 * 128];   // [s][d], elem col ^= (row&7)<<3
    __shared__ alignas(16) bf16 sVt[2][128 * 64];  // [d][s], elem col ^= (row&7)<<3
    __shared__ alignas(16) bf16 sP[8][16 * 64];    // per-wave, col ^= S2(row)<<3

    const int tid  = threadIdx.x;
    const int lane = tid & 63;
    const int w    = tid >> 6;       // 0..7
    const int l15  = lane & 15;
    const int l4   = lane >> 4;
    const int h    = blockIdx.y;
    const int hk   = h >> 2;
    const int qtb  = (int)gridDim.x - 1 - (int)blockIdx.x;  // heavy blocks first
    const int q0   = qtb * 128;
    const float scale = 0.08838834764831845f; // 1/sqrt(128)

    const bf16* Kbase = Kp + hk * HD;
    const bf16* Vbase = Vp + hk * HD;

    // Q fragments (held in registers for whole kernel)
    bf16x8 qf[4];
    const int rbase = q0 + w * 16;
    const int qrow  = rbase + l15;
#pragma unroll
    for (int ks = 0; ks < 4; ++ks)
        qf[ks] = *(const bf16x8*)(Q + (size_t)qrow * HID + h * HD + ks * 32 + l4 * 8);

    f32x4 acc_o[8] = {};
    float mrow[4], lrow[4];
#pragma unroll
    for (int i = 0; i < 4; ++i) { mrow[i] = -1e30f; lrow[i] = 0.f; }

    // --- staging helpers (split across 8 waves) ---
    auto stageK = [&](int t, int buf) {
#pragma unroll
        for (int j = 0; j < 2; ++j) {
            const int c   = w * 2 + j;
            const int row = c * 4 + l4;
            const int col = (l15 * 8) ^ ((row & 7) << 3);
            gload_lds16(Kbase + (size_t)(t * 64 + row) * KVLD + col, &sK[buf][c * 512]);
        }
    };
    auto loadV = [&](int t, bf16x8* vr) {
#pragma unroll
        for (int r2 = 0; r2 < 2; ++r2) {
            const int c = r2 * 8 + w;
            vr[r2] = *(const bf16x8*)(Vbase + (size_t)(t * 64 + lane) * KVLD + c * 8);
        }
    };
    auto writeV = [&](const bf16x8* vr, int buf) {
#pragma unroll
        for (int r2 = 0; r2 < 2; ++r2) {
            const int c = r2 * 8 + w;
#pragma unroll
            for (int e = 0; e < 8; ++e) {
                const int row = c * 8 + e;                 // d-index; row&7 == e
                sVt[buf][row * 64 + (lane ^ (e << 3))] = vr[r2][e];
            }
        }
    };

    const int nt = 2 * qtb + 2;  // causal: s-tiles covering rows <= q0+127

    // prologue: stage tile 0 into buf 0
    bf16x8 vreg[2];
    loadV(0, vreg);
    stageK(0, 0);
    writeV(vreg, 0);
    __syncthreads();

    int cur = 0;
    for (int t = 0; t < nt; ++t) {
        const int s0 = t * 64;
        const bool pf = (t + 1 < nt);
        if (pf) {               // issue next-tile loads early (latency hides under compute)
            loadV(t + 1, vreg); // V first: its reg-use wait leaves K gload_lds in flight
            stageK(t + 1, cur ^ 1);
        }

        // waves whose rows are all above this s-tile contribute identity updates: skip
        if (s0 <= rbase + 15) {
            // QK^T: this wave's 16 q-rows x all 64 s-cols
            f32x4 accs[4] = {};
#pragma unroll
            for (int ks = 0; ks < 4; ++ks) {
#pragma unroll
                for (int j = 0; j < 4; ++j) {
                    const int krow = j * 16 + l15;
                    bf16x8 kb = *(const bf16x8*)&sK[cur][krow * 128 + ((ks * 32 + l4 * 8) ^ ((krow & 7) << 3))];
                    accs[j] = __builtin_amdgcn_mfma_f32_16x16x32_bf16(qf[ks], kb, accs[j], 0, 0, 0);
                }
            }

            // scale (+ mask only when the diagonal crosses this wave's rows)
            float sc[4][4];
            float tmax[4] = {-1e30f, -1e30f, -1e30f, -1e30f};
            const bool needMask = (s0 + 63 > rbase);   // wave-uniform
            if (needMask) {
#pragma unroll
                for (int j = 0; j < 4; ++j) {
                    const int scol = s0 + j * 16 + l15;
#pragma unroll
                    for (int i = 0; i < 4; ++i) {
                        const int r = rbase + l4 * 4 + i;
                        float v = accs[j][i] * scale;
                        if (scol > r) v = -1e30f;
                        sc[j][i] = v;
                        tmax[i] = fmaxf(tmax[i], v);
                    }
                }
            } else {
#pragma unroll
                for (int j = 0; j < 4; ++j)
#pragma unroll
                    for (int i = 0; i < 4; ++i) {
                        const float v = accs[j][i] * scale;
                        sc[j][i] = v;
                        tmax[i] = fmaxf(tmax[i], v);
                    }
            }
            // row-max reduce across the 16 lanes holding this row group
#pragma unroll
            for (int i = 0; i < 4; ++i) {
#pragma unroll
                for (int msk = 1; msk < 16; msk <<= 1)
                    tmax[i] = fmaxf(tmax[i], __shfl_xor(tmax[i], msk));
            }
            float alpha[4];
#pragma unroll
            for (int i = 0; i < 4; ++i) {
                const float nm = fmaxf(mrow[i], tmax[i]);
                alpha[i] = __expf(mrow[i] - nm);
                mrow[i]  = nm;
            }
            float rsum[4] = {0.f, 0.f, 0.f, 0.f};
#pragma unroll
            for (int j = 0; j < 4; ++j)
#pragma unroll
                for (int i = 0; i < 4; ++i) {
                    const float p = __expf(sc[j][i] - mrow[i]);
                    sc[j][i] = p;
                    rsum[i] += p;
                }
#pragma unroll
            for (int i = 0; i < 4; ++i) {
#pragma unroll
                for (int msk = 1; msk < 16; msk <<= 1)
                    rsum[i] += __shfl_xor(rsum[i], msk);
                lrow[i] = lrow[i] * alpha[i] + rsum[i];
            }
#pragma unroll
            for (int d = 0; d < 8; ++d)
#pragma unroll
                for (int i = 0; i < 4; ++i) acc_o[d][i] *= alpha[i];

            // P -> LDS (bf16), per-wave buffer (wave-private: no barrier needed)
#pragma unroll
            for (int j = 0; j < 4; ++j)
#pragma unroll
                for (int i = 0; i < 4; ++i) {
                    const int prow = l4 * 4 + i;
                    const int s2   = (prow & 7) ^ ((prow >> 3) << 1);
                    sP[w][prow * 64 + ((j * 16 + l15) ^ (s2 << 3))] = (bf16)sc[j][i];
                }

            // PV: out[16][128] += P[16][64] * V[64][128]
#pragma unroll
            for (int kk = 0; kk < 2; ++kk) {
                const int s2l = (l15 & 7) ^ ((l15 >> 3) << 1);
                bf16x8 pa = *(const bf16x8*)&sP[w][l15 * 64 + ((kk * 32 + l4 * 8) ^ (s2l << 3))];
#pragma unroll
                for (int d = 0; d < 8; ++d) {
                    const int vrow = d * 16 + l15;
                    bf16x8 vb = *(const bf16x8*)&sVt[cur][vrow * 64 + ((kk * 32 + l4 * 8) ^ ((vrow & 7) << 3))];
                    acc_o[d] = __builtin_amdgcn_mfma_f32_16x16x32_bf16(pa, vb, acc_o[d], 0, 0, 0);
                }
            }
        }

        // write prefetched V into the other buffer (nobody reads it yet)
        if (pf) writeV(vreg, cur ^ 1);

        __syncthreads();   // drains vmcnt (K gload_lds) + lgkm; buffers swap
        cur ^= 1;
    }

    // epilogue: normalize (reciprocal, not divide) and store
    float rinv[4];
#pragma unroll
    for (int i = 0; i < 4; ++i) rinv[i] = __frcp_rn(lrow[i]);
#pragma unroll
    for (int d = 0; d < 8; ++d)
#pragma unroll
        for (int i = 0; i < 4; ++i) {
            const float v = acc_o[d][i] * rinv[i];
            O[(size_t)(rbase + l4 * 4 + i) * HID + h * HD + d * 16 + l15] = (bf16)v;
        }
}

// ---------------------------------------------------------------------------
extern "C" void kernel_launch(void* const* d_in, const int* in_sizes, int n_in,
                              void* d_out, int out_size, void* d_ws, size_t ws_size,
                              hipStream_t stream) {
    const float* hx = (const float*)d_in[0];
    // d_in[1] = attention_mask (exact causal) -- applied analytically
    const float* wq = (const float*)d_in[2];
    const float* wk = (const float*)d_in[3];
    const float* wv = (const float*)d_in[4];
    const float* wo = (const float*)d_in[5];
    float* out = (float*)d_out;

    // workspace layout (bf16), weight buffer reused serially: ~92 MB total
    bf16* Xb   = (bf16*)d_ws;            // 2048*4096
    bf16* Wbuf = Xb + 8388608;           // 4096*4096 (wq / wk|wv / wo reuse)
    bf16* Qb   = Wbuf + 16777216;        // 2048*4096
    bf16* KVb  = Qb + 8388608;           // 2048*2048 (K cols 0..1023 | V cols 1024..2047)
    bf16* Ob   = KVb + 4194304;          // 2048*4096

    auto cast = [&](const float* src, bf16* dst, int n) {
        int n4 = n / 4;
        int blocks = (n4 + 255) / 256;
        if (blocks > 2048) blocks = 2048;
        cast_f32_bf16<<<blocks, 256, 0, stream>>>(src, dst, n4);
    };

    cast(hx, Xb, 2048 * 4096);

    cast(wq, Wbuf, 4096 * 4096);
    gemm_bt<bf16><<<dim3(32, 16), 256, 0, stream>>>(Xb, Wbuf, Qb, 2048, 4096, 4096);

    // merged K|V projection: one N=2048 GEMM (full-chip grid, one launch)
    cast(wk, Wbuf, 1024 * 4096);
    cast(wv, Wbuf + 4194304, 1024 * 4096);
    gemm_bt<bf16><<<dim3(16, 16), 256, 0, stream>>>(Xb, Wbuf, KVb, 2048, 2048, 4096);

    attn_kernel<<<dim3(16, 32), 512, 0, stream>>>(Qb, KVb, KVb + 1024, Ob);

    cast(wo, Wbuf, 4096 * 4096);
    gemm_bt<float><<<dim3(32, 16), 256, 0, stream>>>(Ob, Wbuf, out, 2048, 4096, 4096);
}

// Round 5
// 445.580 us; speedup vs baseline: 2.0447x; 1.1778x over previous
//
#include <hip/hip_runtime.h>
#include <hip/hip_bf16.h>
#include <cstdint>
#include <cstddef>

typedef __bf16 bf16;
typedef __bf16 bf16x4 __attribute__((ext_vector_type(4)));
typedef __bf16 bf16x8 __attribute__((ext_vector_type(8)));
typedef float  f32x4  __attribute__((ext_vector_type(4)));

#define S_LEN 2048
#define HID   4096
#define NH    32
#define NKV   8
#define HD    128
#define KVLD  2048   // merged K|V buffer row stride

// ---------------------------------------------------------------------------
// async global->LDS, 16B per lane. LDS dest is wave-uniform base + lane*16.
__device__ __forceinline__ void gload_lds16(const bf16* g, bf16* l) {
    __builtin_amdgcn_global_load_lds(
        (const __attribute__((address_space(1))) void*)g,
        (__attribute__((address_space(3))) void*)l,
        16, 0, 0);
}

// ---------------------------------------------------------------------------
// fp32 -> bf16 cast (vectorized float4 -> bf16x4)
__global__ void cast_f32_bf16(const float* __restrict__ in, bf16* __restrict__ out, int n4) {
    int idx    = blockIdx.x * blockDim.x + threadIdx.x;
    int stride = gridDim.x * blockDim.x;
    for (int i = idx; i < n4; i += stride) {
        float4 v = ((const float4*)in)[i];
        bf16x4 o = { (bf16)v.x, (bf16)v.y, (bf16)v.z, (bf16)v.w };
        ((bf16x4*)out)[i] = o;
    }
}

// ---------------------------------------------------------------------------
// GEMM: C[m][n] = sum_k A[m][k] * B[n][k]   (both K-major; B is a weight [N][K])
// 128x128 tile, BK=32, 256 threads = 4 waves (2x2), each wave 64x64 (4x4 frags),
// 16x16x32 bf16 MFMA, global_load_lds width-16 staging (m97 structure).
template <typename OUT_T>
__global__ __launch_bounds__(256) void gemm_bt(const bf16* __restrict__ A,
                                               const bf16* __restrict__ B,
                                               OUT_T* __restrict__ C,
                                               int M, int N, int K) {
    __shared__ alignas(16) bf16 sA[128 * 32];
    __shared__ alignas(16) bf16 sB[128 * 32];

    const int tid  = threadIdx.x;
    const int lane = tid & 63;
    const int w    = tid >> 6;      // 0..3
    const int wr   = w >> 1;        // wave row (0..1)
    const int wc   = w & 1;         // wave col (0..1)
    const int l15  = lane & 15;
    const int l4   = lane >> 4;
    const int m0   = blockIdx.y * 128;
    const int n0   = blockIdx.x * 128;

    f32x4 acc[4][4] = {};

    // staging: 8 chunks of 1KB per tile; wave w stages chunks w*2, w*2+1
    const int c0 = w * 2;
    const int c1 = w * 2 + 1;
    const int srow0 = c0 * 16 + (lane >> 2);
    const int srow1 = c1 * 16 + (lane >> 2);
    const int scol  = (lane & 3) * 8;
    const bf16* aS0 = A + (size_t)(m0 + srow0) * K + scol;
    const bf16* aS1 = A + (size_t)(m0 + srow1) * K + scol;
    const bf16* bS0 = B + (size_t)(n0 + srow0) * K + scol;
    const bf16* bS1 = B + (size_t)(n0 + srow1) * K + scol;
    bf16* aD0 = &sA[c0 * 512];
    bf16* aD1 = &sA[c1 * 512];
    bf16* bD0 = &sB[c0 * 512];
    bf16* bD1 = &sB[c1 * 512];

    for (int k0 = 0; k0 < K; k0 += 32) {
        gload_lds16(aS0 + k0, aD0);
        gload_lds16(aS1 + k0, aD1);
        gload_lds16(bS0 + k0, bD0);
        gload_lds16(bS1 + k0, bD1);
        __syncthreads();

        bf16x8 af[4], bfr[4];
#pragma unroll
        for (int i = 0; i < 4; ++i)
            af[i] = *(const bf16x8*)&sA[(wr * 64 + i * 16 + l15) * 32 + l4 * 8];
#pragma unroll
        for (int j = 0; j < 4; ++j)
            bfr[j] = *(const bf16x8*)&sB[(wc * 64 + j * 16 + l15) * 32 + l4 * 8];
#pragma unroll
        for (int i = 0; i < 4; ++i)
#pragma unroll
            for (int j = 0; j < 4; ++j)
                acc[i][j] = __builtin_amdgcn_mfma_f32_16x16x32_bf16(af[i], bfr[j], acc[i][j], 0, 0, 0);
        __syncthreads();
    }

    // epilogue: C/D layout col = lane&15, row = (lane>>4)*4 + reg
#pragma unroll
    for (int i = 0; i < 4; ++i) {
        const int row = m0 + wr * 64 + i * 16 + l4 * 4;
#pragma unroll
        for (int j = 0; j < 4; ++j) {
            const int col = n0 + wc * 64 + j * 16 + l15;
#pragma unroll
            for (int r = 0; r < 4; ++r)
                C[(size_t)(row + r) * N + col] = (OUT_T)acc[i][j][r];
        }
    }
}

// ---------------------------------------------------------------------------
// Flash attention, causal, GQA 4:1. Block = 8 waves; processes TWO q-strips
// (128 rows each): strips b and 15-b -> uniform 34 tile-units/block, grid
// 8x32 = 256 blocks = 1/CU, no straggler tail. Double-buffered K (gload_lds,
// pre-swizzled source) and V (reg-staged, transposed+swizzled write). One
// barrier per tile. Defer-max (T13): rescale only when tile max grows >8.
// Scale folded into exp2 (scores kept raw).
__global__ __launch_bounds__(512) void attn_kernel(const bf16* __restrict__ Q,
                                                   const bf16* __restrict__ Kp,
                                                   const bf16* __restrict__ Vp,
                                                   bf16* __restrict__ O) {
    __shared__ alignas(16) bf16 sK[2][64 * 128];   // [s][d], elem col ^= (row&7)<<3
    __shared__ alignas(16) bf16 sVt[2][128 * 64];  // [d][s], elem col ^= (row&7)<<3
    __shared__ alignas(16) bf16 sP[8][16 * 64];    // per-wave, col ^= S2(row)<<3

    const int tid  = threadIdx.x;
    const int lane = tid & 63;
    const int w    = tid >> 6;       // 0..7
    const int l15  = lane & 15;
    const int l4   = lane >> 4;
    const int h    = blockIdx.y;
    const int hk   = h >> 2;
    const int b    = blockIdx.x;                 // 0..7
    const int qH   = 15 - b;                     // heavy strip
    const int qL   = b;                          // light strip
    const float C2     = 0.12751744f;            // scale * log2(e)
    const float THRRAW = 90.5f;                  // 8 / scale (defer-max threshold)

    const bf16* Kbase = Kp + hk * HD;
    const bf16* Vbase = Vp + hk * HD;

    // Q fragments for both strips (held in registers for whole kernel)
    const int rbH = qH * 128 + w * 16;
    const int rbL = qL * 128 + w * 16;
    bf16x8 qfH[4], qfL[4];
#pragma unroll
    for (int ks = 0; ks < 4; ++ks) {
        qfH[ks] = *(const bf16x8*)(Q + (size_t)(rbH + l15) * HID + h * HD + ks * 32 + l4 * 8);
        qfL[ks] = *(const bf16x8*)(Q + (size_t)(rbL + l15) * HID + h * HD + ks * 32 + l4 * 8);
    }

    f32x4 accH[8] = {}, accL[8] = {};
    float mH[4], lH[4], mL[4], lL[4];
#pragma unroll
    for (int i = 0; i < 4; ++i) { mH[i] = -3e38f; lH[i] = 0.f; mL[i] = -3e38f; lL[i] = 0.f; }

    // --- staging helpers (split across 8 waves) ---
    auto stageK = [&](int t, int buf) {
#pragma unroll
        for (int j = 0; j < 2; ++j) {
            const int c   = w * 2 + j;
            const int row = c * 4 + l4;
            const int col = (l15 * 8) ^ ((row & 7) << 3);
            gload_lds16(Kbase + (size_t)(t * 64 + row) * KVLD + col, &sK[buf][c * 512]);
        }
    };
    auto loadV = [&](int t, bf16x8* vr) {
#pragma unroll
        for (int r2 = 0; r2 < 2; ++r2) {
            const int c = r2 * 8 + w;
            vr[r2] = *(const bf16x8*)(Vbase + (size_t)(t * 64 + lane) * KVLD + c * 8);
        }
    };
    auto writeV = [&](const bf16x8* vr, int buf) {
#pragma unroll
        for (int r2 = 0; r2 < 2; ++r2) {
            const int c = r2 * 8 + w;
#pragma unroll
            for (int e = 0; e < 8; ++e) {
                const int row = c * 8 + e;                 // d-index; row&7 == e
                sVt[buf][row * 64 + (lane ^ (e << 3))] = vr[r2][e];
            }
        }
    };

    // --- one strip's QK^T/softmax/PV for one tile ---
    auto strip = [&](const bf16x8* qf, f32x4* acc_o, float* mrow, float* lrow,
                     int rbase, int s0, int cur) {
        if (s0 > rbase + 15) return;   // wave-uniform: rows entirely above tile
        // QK^T: this wave's 16 q-rows x all 64 s-cols (raw scores)
        f32x4 accs[4] = {};
#pragma unroll
        for (int ks = 0; ks < 4; ++ks) {
#pragma unroll
            for (int j = 0; j < 4; ++j) {
                const int krow = j * 16 + l15;
                bf16x8 kb = *(const bf16x8*)&sK[cur][krow * 128 + ((ks * 32 + l4 * 8) ^ ((krow & 7) << 3))];
                accs[j] = __builtin_amdgcn_mfma_f32_16x16x32_bf16(qf[ks], kb, accs[j], 0, 0, 0);
            }
        }

        float sc[4][4];
        float tmax[4] = {-3e38f, -3e38f, -3e38f, -3e38f};
        const bool needMask = (s0 + 63 > rbase);   // wave-uniform
        if (needMask) {
#pragma unroll
            for (int j = 0; j < 4; ++j) {
                const int scol = s0 + j * 16 + l15;
#pragma unroll
                for (int i = 0; i < 4; ++i) {
                    const int r = rbase + l4 * 4 + i;
                    float v = accs[j][i];
                    if (scol > r) v = -3e38f;
                    sc[j][i] = v;
                    tmax[i] = fmaxf(tmax[i], v);
                }
            }
        } else {
#pragma unroll
            for (int j = 0; j < 4; ++j)
#pragma unroll
                for (int i = 0; i < 4; ++i) {
                    const float v = accs[j][i];
                    sc[j][i] = v;
                    tmax[i] = fmaxf(tmax[i], v);
                }
        }
        // row-max reduce across the 16 lanes holding this row group
#pragma unroll
        for (int i = 0; i < 4; ++i) {
#pragma unroll
            for (int msk = 1; msk < 16; msk <<= 1)
                tmax[i] = fmaxf(tmax[i], __shfl_xor(tmax[i], msk));
        }
        // defer-max: rescale only if some row's max grew past threshold
        bool up = false;
#pragma unroll
        for (int i = 0; i < 4; ++i) up = up || (tmax[i] > mrow[i] + THRRAW);
        if (__any((int)up)) {
#pragma unroll
            for (int i = 0; i < 4; ++i) {
                const float nm = fmaxf(mrow[i], tmax[i]);
                const float alpha = exp2f((mrow[i] - nm) * C2);
                mrow[i] = nm;
                lrow[i] *= alpha;
#pragma unroll
                for (int d = 0; d < 8; ++d) acc_o[d][i] *= alpha;
            }
        }
        float rsum[4] = {0.f, 0.f, 0.f, 0.f};
#pragma unroll
        for (int j = 0; j < 4; ++j)
#pragma unroll
            for (int i = 0; i < 4; ++i) {
                const float p = exp2f((sc[j][i] - mrow[i]) * C2);
                sc[j][i] = p;
                rsum[i] += p;
            }
#pragma unroll
        for (int i = 0; i < 4; ++i) {
#pragma unroll
            for (int msk = 1; msk < 16; msk <<= 1)
                rsum[i] += __shfl_xor(rsum[i], msk);
            lrow[i] += rsum[i];
        }

        // P -> LDS (bf16), per-wave buffer (wave-private: no barrier needed)
#pragma unroll
        for (int j = 0; j < 4; ++j)
#pragma unroll
            for (int i = 0; i < 4; ++i) {
                const int prow = l4 * 4 + i;
                const int s2   = (prow & 7) ^ ((prow >> 3) << 1);
                sP[w][prow * 64 + ((j * 16 + l15) ^ (s2 << 3))] = (bf16)sc[j][i];
            }

        // PV: out[16][128] += P[16][64] * V[64][128]
#pragma unroll
        for (int kk = 0; kk < 2; ++kk) {
            const int s2l = (l15 & 7) ^ ((l15 >> 3) << 1);
            bf16x8 pa = *(const bf16x8*)&sP[w][l15 * 64 + ((kk * 32 + l4 * 8) ^ (s2l << 3))];
#pragma unroll
            for (int d = 0; d < 8; ++d) {
                const int vrow = d * 16 + l15;
                bf16x8 vb = *(const bf16x8*)&sVt[cur][vrow * 64 + ((kk * 32 + l4 * 8) ^ ((vrow & 7) << 3))];
                acc_o[d] = __builtin_amdgcn_mfma_f32_16x16x32_bf16(pa, vb, acc_o[d], 0, 0, 0);
            }
        }
    };

    const int ntH = 2 * qH + 2;   // tiles for heavy strip (= loop bound)
    const int ntL = 2 * qL + 2;   // tiles for light strip

    // prologue: stage tile 0 into buf 0
    bf16x8 vreg[2];
    loadV(0, vreg);
    stageK(0, 0);
    writeV(vreg, 0);
    __syncthreads();

    int cur = 0;
    for (int t = 0; t < ntH; ++t) {
        const int s0 = t * 64;
        const bool pf = (t + 1 < ntH);
        if (pf) {               // issue next-tile loads early (latency hides under compute)
            loadV(t + 1, vreg); // V first: its reg-use wait leaves K gload_lds in flight
            stageK(t + 1, cur ^ 1);
        }

        strip(qfH, accH, mH, lH, rbH, s0, cur);
        if (t < ntL) strip(qfL, accL, mL, lL, rbL, s0, cur);

        // write prefetched V into the other buffer (nobody reads it yet)
        if (pf) writeV(vreg, cur ^ 1);

        __syncthreads();   // drains vmcnt (K gload_lds) + lgkm; buffers swap
        cur ^= 1;
    }

    // epilogue: normalize (reciprocal) and store both strips
    float rH[4], rL[4];
#pragma unroll
    for (int i = 0; i < 4; ++i) { rH[i] = __frcp_rn(lH[i]); rL[i] = __frcp_rn(lL[i]); }
#pragma unroll
    for (int d = 0; d < 8; ++d)
#pragma unroll
        for (int i = 0; i < 4; ++i) {
            O[(size_t)(rbH + l4 * 4 + i) * HID + h * HD + d * 16 + l15] = (bf16)(accH[d][i] * rH[i]);
            O[(size_t)(rbL + l4 * 4 + i) * HID + h * HD + d * 16 + l15] = (bf16)(accL[d][i] * rL[i]);
        }
}

// ---------------------------------------------------------------------------
extern "C" void kernel_launch(void* const* d_in, const int* in_sizes, int n_in,
                              void* d_out, int out_size, void* d_ws, size_t ws_size,
                              hipStream_t stream) {
    const float* hx = (const float*)d_in[0];
    // d_in[1] = attention_mask (exact causal) -- applied analytically
    const float* wq = (const float*)d_in[2];
    const float* wk = (const float*)d_in[3];
    const float* wv = (const float*)d_in[4];
    const float* wo = (const float*)d_in[5];
    float* out = (float*)d_out;

    // workspace layout (bf16), weight buffer reused serially: ~92 MB total
    bf16* Xb   = (bf16*)d_ws;            // 2048*4096
    bf16* Wbuf = Xb + 8388608;           // 4096*4096 (wq / wk|wv / wo reuse)
    bf16* Qb   = Wbuf + 16777216;        // 2048*4096
    bf16* KVb  = Qb + 8388608;           // 2048*2048 (K cols 0..1023 | V cols 1024..2047)
    bf16* Ob   = KVb + 4194304;          // 2048*4096

    auto cast = [&](const float* src, bf16* dst, int n) {
        int n4 = n / 4;
        int blocks = (n4 + 255) / 256;
        if (blocks > 2048) blocks = 2048;
        cast_f32_bf16<<<blocks, 256, 0, stream>>>(src, dst, n4);
    };

    cast(hx, Xb, 2048 * 4096);

    cast(wq, Wbuf, 4096 * 4096);
    gemm_bt<bf16><<<dim3(32, 16), 256, 0, stream>>>(Xb, Wbuf, Qb, 2048, 4096, 4096);

    // merged K|V projection: one N=2048 GEMM (full-chip grid, one launch)
    cast(wk, Wbuf, 1024 * 4096);
    cast(wv, Wbuf + 4194304, 1024 * 4096);
    gemm_bt<bf16><<<dim3(16, 16), 256, 0, stream>>>(Xb, Wbuf, KVb, 2048, 2048, 4096);

    attn_kernel<<<dim3(8, 32), 512, 0, stream>>>(Qb, KVb, KVb + 1024, Ob);

    cast(wo, Wbuf, 4096 * 4096);
    gemm_bt<float><<<dim3(32, 16), 256, 0, stream>>>(Ob, Wbuf, out, 2048, 4096, 4096);
}

// Round 6
// 337.071 us; speedup vs baseline: 2.7029x; 1.3219x over previous
//
#include <hip/hip_runtime.h>
#include <hip/hip_bf16.h>
#include <cstdint>
#include <cstddef>

typedef __bf16 bf16;
typedef __bf16 bf16x4 __attribute__((ext_vector_type(4)));
typedef __bf16 bf16x8 __attribute__((ext_vector_type(8)));
typedef float  f32x4  __attribute__((ext_vector_type(4)));

#define S_LEN 2048
#define HID   4096
#define NH    32
#define NKV   8
#define HD    128
#define KVLD  2048   // merged K|V buffer row stride

// ---------------------------------------------------------------------------
// async global->LDS, 16B per lane. LDS dest is wave-uniform base + lane*16.
__device__ __forceinline__ void gload_lds16(const bf16* g, bf16* l) {
    __builtin_amdgcn_global_load_lds(
        (const __attribute__((address_space(1))) void*)g,
        (__attribute__((address_space(3))) void*)l,
        16, 0, 0);
}

// ---------------------------------------------------------------------------
// fp32 -> bf16 cast (vectorized float4 -> bf16x4)
__global__ void cast_f32_bf16(const float* __restrict__ in, bf16* __restrict__ out, int n4) {
    int idx    = blockIdx.x * blockDim.x + threadIdx.x;
    int stride = gridDim.x * blockDim.x;
    for (int i = idx; i < n4; i += stride) {
        float4 v = ((const float4*)in)[i];
        bf16x4 o = { (bf16)v.x, (bf16)v.y, (bf16)v.z, (bf16)v.w };
        ((bf16x4*)out)[i] = o;
    }
}

// ---------------------------------------------------------------------------
// GEMM: C[m][n] = sum_k A[m][k] * B[n][k]   (both K-major; B is a weight [N][K])
// 128x128 tile, BK=64, double-buffered LDS, 2-phase pipeline (T3-minimal):
// stage tile t+1 BEFORE computing tile t; one barrier per K-tile. LDS tiles
// XOR-swizzled via pre-swizzled global source (rule #21): element (r,c) lives
// at lds[r*64 + (c ^ ((r&7)<<3))] -> fragment reads hit 8 distinct 16B slots.
// 256 threads = 4 waves (2x2), each wave 64x64 (4x4 frags), 16x16x32 MFMA.
template <typename OUT_T>
__global__ __launch_bounds__(256) void gemm_bt(const bf16* __restrict__ A,
                                               const bf16* __restrict__ B,
                                               OUT_T* __restrict__ C,
                                               int M, int N, int K) {
    __shared__ alignas(16) bf16 sA[2][128 * 64];
    __shared__ alignas(16) bf16 sB[2][128 * 64];

    const int tid  = threadIdx.x;
    const int lane = tid & 63;
    const int w    = tid >> 6;      // 0..3
    const int wr   = w >> 1;        // wave row (0..1)
    const int wc   = w & 1;         // wave col (0..1)
    const int l15  = lane & 15;
    const int l4   = lane >> 4;
    const int m0   = blockIdx.y * 128;
    const int n0   = blockIdx.x * 128;

    f32x4 acc[4][4] = {};

    // staging: A/B tile = 128 rows x 64 cols = 16 KB = 16 chunks of 1 KB
    // (8 rows each); wave w stages chunks w*4..w*4+3 of each. Lane covers
    // row = c*8 + (lane>>3), 16 B at source col pre-swizzled so the linear
    // LDS dest realizes the swizzled layout.
    const int rsub = lane >> 3;                       // row within chunk (0..7)
    const int scol = ((lane & 7) * 8) ^ (rsub << 3);  // pre-swizzled source col

    auto stage = [&](int t, int buf) {
#pragma unroll
        for (int j = 0; j < 4; ++j) {
            const int c   = w * 4 + j;
            const int row = c * 8 + rsub;
            gload_lds16(A + (size_t)(m0 + row) * K + t * 64 + scol, &sA[buf][c * 512]);
            gload_lds16(B + (size_t)(n0 + row) * K + t * 64 + scol, &sB[buf][c * 512]);
        }
    };

    const int nt = K >> 6;   // K-tiles of 64

    stage(0, 0);
    __syncthreads();         // implicit vmcnt(0) drain

    int buf = 0;
    for (int t = 0; t < nt; ++t) {
        if (t + 1 < nt) stage(t + 1, buf ^ 1);   // prefetch hides under compute

        bf16x8 af[2][4], bfr[2][4];
#pragma unroll
        for (int kk = 0; kk < 2; ++kk) {
#pragma unroll
            for (int i = 0; i < 4; ++i) {
                const int ra = wr * 64 + i * 16 + l15;
                af[kk][i]  = *(const bf16x8*)&sA[buf][ra * 64 + ((kk * 32 + l4 * 8) ^ ((ra & 7) << 3))];
                const int rb = wc * 64 + i * 16 + l15;
                bfr[kk][i] = *(const bf16x8*)&sB[buf][rb * 64 + ((kk * 32 + l4 * 8) ^ ((rb & 7) << 3))];
            }
        }
#pragma unroll
        for (int kk = 0; kk < 2; ++kk)
#pragma unroll
            for (int i = 0; i < 4; ++i)
#pragma unroll
                for (int j = 0; j < 4; ++j)
                    acc[i][j] = __builtin_amdgcn_mfma_f32_16x16x32_bf16(af[kk][i], bfr[kk][j], acc[i][j], 0, 0, 0);

        __syncthreads();     // drains vmcnt (prefetch done); protects buf reuse
        buf ^= 1;
    }

    // epilogue: C/D layout col = lane&15, row = (lane>>4)*4 + reg
#pragma unroll
    for (int i = 0; i < 4; ++i) {
        const int row = m0 + wr * 64 + i * 16 + l4 * 4;
#pragma unroll
        for (int j = 0; j < 4; ++j) {
            const int col = n0 + wc * 64 + j * 16 + l15;
#pragma unroll
            for (int r = 0; r < 4; ++r)
                C[(size_t)(row + r) * N + col] = (OUT_T)acc[i][j][r];
        }
    }
}

// ---------------------------------------------------------------------------
// Flash attention, causal, GQA 4:1. Block = 8 waves; processes TWO q-strips
// (128 rows each): strips b and 15-b -> uniform 34 tile-units/block, grid
// 8x32 = 256 blocks = 1/CU, no straggler tail. Double-buffered K (gload_lds,
// pre-swizzled source) and V (reg-staged, transposed+swizzled write). One
// barrier per tile. Defer-max (T13): rescale only when tile max grows >8.
// Scale folded into exp2 (scores kept raw).
__global__ __launch_bounds__(512) void attn_kernel(const bf16* __restrict__ Q,
                                                   const bf16* __restrict__ Kp,
                                                   const bf16* __restrict__ Vp,
                                                   bf16* __restrict__ O) {
    __shared__ alignas(16) bf16 sK[2][64 * 128];   // [s][d], elem col ^= (row&7)<<3
    __shared__ alignas(16) bf16 sVt[2][128 * 64];  // [d][s], elem col ^= (row&7)<<3
    __shared__ alignas(16) bf16 sP[8][16 * 64];    // per-wave, col ^= S2(row)<<3

    const int tid  = threadIdx.x;
    const int lane = tid & 63;
    const int w    = tid >> 6;       // 0..7
    const int l15  = lane & 15;
    const int l4   = lane >> 4;
    const int h    = blockIdx.y;
    const int hk   = h >> 2;
    const int b    = blockIdx.x;                 // 0..7
    const int qH   = 15 - b;                     // heavy strip
    const int qL   = b;                          // light strip
    const float C2     = 0.12751744f;            // scale * log2(e)
    const float THRRAW = 90.5f;                  // 8 / scale (defer-max threshold)

    const bf16* Kbase = Kp + hk * HD;
    const bf16* Vbase = Vp + hk * HD;

    // Q fragments for both strips (held in registers for whole kernel)
    const int rbH = qH * 128 + w * 16;
    const int rbL = qL * 128 + w * 16;
    bf16x8 qfH[4], qfL[4];
#pragma unroll
    for (int ks = 0; ks < 4; ++ks) {
        qfH[ks] = *(const bf16x8*)(Q + (size_t)(rbH + l15) * HID + h * HD + ks * 32 + l4 * 8);
        qfL[ks] = *(const bf16x8*)(Q + (size_t)(rbL + l15) * HID + h * HD + ks * 32 + l4 * 8);
    }

    f32x4 accH[8] = {}, accL[8] = {};
    float mH[4], lH[4], mL[4], lL[4];
#pragma unroll
    for (int i = 0; i < 4; ++i) { mH[i] = -3e38f; lH[i] = 0.f; mL[i] = -3e38f; lL[i] = 0.f; }

    // --- staging helpers (split across 8 waves) ---
    auto stageK = [&](int t, int buf) {
#pragma unroll
        for (int j = 0; j < 2; ++j) {
            const int c   = w * 2 + j;
            const int row = c * 4 + l4;
            const int col = (l15 * 8) ^ ((row & 7) << 3);
            gload_lds16(Kbase + (size_t)(t * 64 + row) * KVLD + col, &sK[buf][c * 512]);
        }
    };
    auto loadV = [&](int t, bf16x8* vr) {
#pragma unroll
        for (int r2 = 0; r2 < 2; ++r2) {
            const int c = r2 * 8 + w;
            vr[r2] = *(const bf16x8*)(Vbase + (size_t)(t * 64 + lane) * KVLD + c * 8);
        }
    };
    auto writeV = [&](const bf16x8* vr, int buf) {
#pragma unroll
        for (int r2 = 0; r2 < 2; ++r2) {
            const int c = r2 * 8 + w;
#pragma unroll
            for (int e = 0; e < 8; ++e) {
                const int row = c * 8 + e;                 // d-index; row&7 == e
                sVt[buf][row * 64 + (lane ^ (e << 3))] = vr[r2][e];
            }
        }
    };

    // --- one strip's QK^T/softmax/PV for one tile ---
    auto strip = [&](const bf16x8* qf, f32x4* acc_o, float* mrow, float* lrow,
                     int rbase, int s0, int cur) {
        if (s0 > rbase + 15) return;   // wave-uniform: rows entirely above tile
        // QK^T: this wave's 16 q-rows x all 64 s-cols (raw scores)
        f32x4 accs[4] = {};
#pragma unroll
        for (int ks = 0; ks < 4; ++ks) {
#pragma unroll
            for (int j = 0; j < 4; ++j) {
                const int krow = j * 16 + l15;
                bf16x8 kb = *(const bf16x8*)&sK[cur][krow * 128 + ((ks * 32 + l4 * 8) ^ ((krow & 7) << 3))];
                accs[j] = __builtin_amdgcn_mfma_f32_16x16x32_bf16(qf[ks], kb, accs[j], 0, 0, 0);
            }
        }

        float sc[4][4];
        float tmax[4] = {-3e38f, -3e38f, -3e38f, -3e38f};
        const bool needMask = (s0 + 63 > rbase);   // wave-uniform
        if (needMask) {
#pragma unroll
            for (int j = 0; j < 4; ++j) {
                const int scol = s0 + j * 16 + l15;
#pragma unroll
                for (int i = 0; i < 4; ++i) {
                    const int r = rbase + l4 * 4 + i;
                    float v = accs[j][i];
                    if (scol > r) v = -3e38f;
                    sc[j][i] = v;
                    tmax[i] = fmaxf(tmax[i], v);
                }
            }
        } else {
#pragma unroll
            for (int j = 0; j < 4; ++j)
#pragma unroll
                for (int i = 0; i < 4; ++i) {
                    const float v = accs[j][i];
                    sc[j][i] = v;
                    tmax[i] = fmaxf(tmax[i], v);
                }
        }
        // row-max reduce across the 16 lanes holding this row group
#pragma unroll
        for (int i = 0; i < 4; ++i) {
#pragma unroll
            for (int msk = 1; msk < 16; msk <<= 1)
                tmax[i] = fmaxf(tmax[i], __shfl_xor(tmax[i], msk));
        }
        // defer-max: rescale only if some row's max grew past threshold
        bool up = false;
#pragma unroll
        for (int i = 0; i < 4; ++i) up = up || (tmax[i] > mrow[i] + THRRAW);
        if (__any((int)up)) {
#pragma unroll
            for (int i = 0; i < 4; ++i) {
                const float nm = fmaxf(mrow[i], tmax[i]);
                const float alpha = exp2f((mrow[i] - nm) * C2);
                mrow[i] = nm;
                lrow[i] *= alpha;
#pragma unroll
                for (int d = 0; d < 8; ++d) acc_o[d][i] *= alpha;
            }
        }
        float rsum[4] = {0.f, 0.f, 0.f, 0.f};
#pragma unroll
        for (int j = 0; j < 4; ++j)
#pragma unroll
            for (int i = 0; i < 4; ++i) {
                const float p = exp2f((sc[j][i] - mrow[i]) * C2);
                sc[j][i] = p;
                rsum[i] += p;
            }
#pragma unroll
        for (int i = 0; i < 4; ++i) {
#pragma unroll
            for (int msk = 1; msk < 16; msk <<= 1)
                rsum[i] += __shfl_xor(rsum[i], msk);
            lrow[i] += rsum[i];
        }

        // P -> LDS (bf16), per-wave buffer (wave-private: no barrier needed)
#pragma unroll
        for (int j = 0; j < 4; ++j)
#pragma unroll
            for (int i = 0; i < 4; ++i) {
                const int prow = l4 * 4 + i;
                const int s2   = (prow & 7) ^ ((prow >> 3) << 1);
                sP[w][prow * 64 + ((j * 16 + l15) ^ (s2 << 3))] = (bf16)sc[j][i];
            }

        // PV: out[16][128] += P[16][64] * V[64][128]
#pragma unroll
        for (int kk = 0; kk < 2; ++kk) {
            const int s2l = (l15 & 7) ^ ((l15 >> 3) << 1);
            bf16x8 pa = *(const bf16x8*)&sP[w][l15 * 64 + ((kk * 32 + l4 * 8) ^ (s2l << 3))];
#pragma unroll
            for (int d = 0; d < 8; ++d) {
                const int vrow = d * 16 + l15;
                bf16x8 vb = *(const bf16x8*)&sVt[cur][vrow * 64 + ((kk * 32 + l4 * 8) ^ ((vrow & 7) << 3))];
                acc_o[d] = __builtin_amdgcn_mfma_f32_16x16x32_bf16(pa, vb, acc_o[d], 0, 0, 0);
            }
        }
    };

    const int ntH = 2 * qH + 2;   // tiles for heavy strip (= loop bound)
    const int ntL = 2 * qL + 2;   // tiles for light strip

    // prologue: stage tile 0 into buf 0
    bf16x8 vreg[2];
    loadV(0, vreg);
    stageK(0, 0);
    writeV(vreg, 0);
    __syncthreads();

    int cur = 0;
    for (int t = 0; t < ntH; ++t) {
        const int s0 = t * 64;
        const bool pf = (t + 1 < ntH);
        if (pf) {               // issue next-tile loads early (latency hides under compute)
            loadV(t + 1, vreg); // V first: its reg-use wait leaves K gload_lds in flight
            stageK(t + 1, cur ^ 1);
        }

        strip(qfH, accH, mH, lH, rbH, s0, cur);
        if (t < ntL) strip(qfL, accL, mL, lL, rbL, s0, cur);

        // write prefetched V into the other buffer (nobody reads it yet)
        if (pf) writeV(vreg, cur ^ 1);

        __syncthreads();   // drains vmcnt (K gload_lds) + lgkm; buffers swap
        cur ^= 1;
    }

    // epilogue: normalize (reciprocal) and store both strips
    float rH[4], rL[4];
#pragma unroll
    for (int i = 0; i < 4; ++i) { rH[i] = __frcp_rn(lH[i]); rL[i] = __frcp_rn(lL[i]); }
#pragma unroll
    for (int d = 0; d < 8; ++d)
#pragma unroll
        for (int i = 0; i < 4; ++i) {
            O[(size_t)(rbH + l4 * 4 + i) * HID + h * HD + d * 16 + l15] = (bf16)(accH[d][i] * rH[i]);
            O[(size_t)(rbL + l4 * 4 + i) * HID + h * HD + d * 16 + l15] = (bf16)(accL[d][i] * rL[i]);
        }
}

// ---------------------------------------------------------------------------
extern "C" void kernel_launch(void* const* d_in, const int* in_sizes, int n_in,
                              void* d_out, int out_size, void* d_ws, size_t ws_size,
                              hipStream_t stream) {
    const float* hx = (const float*)d_in[0];
    // d_in[1] = attention_mask (exact causal) -- applied analytically
    const float* wq = (const float*)d_in[2];
    const float* wk = (const float*)d_in[3];
    const float* wv = (const float*)d_in[4];
    const float* wo = (const float*)d_in[5];
    float* out = (float*)d_out;

    // workspace layout (bf16), weight buffer reused serially: ~92 MB total
    bf16* Xb   = (bf16*)d_ws;            // 2048*4096
    bf16* Wbuf = Xb + 8388608;           // 4096*4096 (wq / wk|wv / wo reuse)
    bf16* Qb   = Wbuf + 16777216;        // 2048*4096
    bf16* KVb  = Qb + 8388608;           // 2048*2048 (K cols 0..1023 | V cols 1024..2047)
    bf16* Ob   = KVb + 4194304;          // 2048*4096

    auto cast = [&](const float* src, bf16* dst, int n) {
        int n4 = n / 4;
        int blocks = (n4 + 255) / 256;
        if (blocks > 2048) blocks = 2048;
        cast_f32_bf16<<<blocks, 256, 0, stream>>>(src, dst, n4);
    };

    cast(hx, Xb, 2048 * 4096);

    cast(wq, Wbuf, 4096 * 4096);
    gemm_bt<bf16><<<dim3(32, 16), 256, 0, stream>>>(Xb, Wbuf, Qb, 2048, 4096, 4096);

    // merged K|V projection: one N=2048 GEMM (full-chip grid, one launch)
    cast(wk, Wbuf, 1024 * 4096);
    cast(wv, Wbuf + 4194304, 1024 * 4096);
    gemm_bt<bf16><<<dim3(16, 16), 256, 0, stream>>>(Xb, Wbuf, KVb, 2048, 2048, 4096);

    attn_kernel<<<dim3(8, 32), 512, 0, stream>>>(Qb, KVb, KVb + 1024, Ob);

    cast(wo, Wbuf, 4096 * 4096);
    gemm_bt<float><<<dim3(32, 16), 256, 0, stream>>>(Ob, Wbuf, out, 2048, 4096, 4096);
}